// Round 2
// baseline (233.044 us; speedup 1.0000x reference)
//
#include <hip/hip_runtime.h>
#include <hip/hip_bf16.h>
#include <math.h>

#define BB 2
#define SS 2048
#define DD 1024
#define HH 16
#define HD 64
#define MM (BB * SS)   // 4096

typedef __bf16 bf16;
typedef __attribute__((ext_vector_type(8))) __bf16 bf16x8;
typedef __attribute__((ext_vector_type(4))) __bf16 bf16x4;
typedef __attribute__((ext_vector_type(4))) float f32x4;

#define QSCL 0.18033688011112042f   // log2(e)/8, folded into Q at projection

// async global->LDS, 16B per lane. LDS dest must be wave-uniform base + lane*16.
__device__ __forceinline__ void glds16(const bf16* g, bf16* l) {
    __builtin_amdgcn_global_load_lds(
        (const __attribute__((address_space(1))) void*)g,
        (__attribute__((address_space(3))) void*)l, 16, 0, 0);
}

// packed f32x2 -> bf16x2 (no builtin on gfx950; T12 primitive)
__device__ __forceinline__ unsigned cvtpk_bf16(float a, float b) {
    unsigned r;
    asm("v_cvt_pk_bf16_f32 %0, %1, %2" : "=v"(r) : "v"(a), "v"(b));
    return r;
}

// ---------------------------------------------------------------------------
// Prep 1: x (fp32) -> xb (bf16).  4M elements, 4/thread.
// ---------------------------------------------------------------------------
__global__ __launch_bounds__(256) void cvt_x(const float* __restrict__ x,
                                             bf16* __restrict__ xb) {
    int i = (blockIdx.x * 256 + threadIdx.x) * 4;
    float4 v = *(const float4*)(x + i);
    bf16x4 o;
    o[0] = (bf16)v.x; o[1] = (bf16)v.y; o[2] = (bf16)v.z; o[3] = (bf16)v.w;
    *(bf16x4*)(xb + i) = o;
}

// ---------------------------------------------------------------------------
// Prep 2: W[k][n] fp32 -> Wt[n][k] bf16 (4 weights via z). 64x64 LDS transpose.
// ---------------------------------------------------------------------------
__global__ __launch_bounds__(256) void cvt_w(
    const float* __restrict__ W0, const float* __restrict__ W1,
    const float* __restrict__ W2, const float* __restrict__ W3,
    bf16* __restrict__ Wt) {
    const float* W = (blockIdx.z == 0) ? W0 : (blockIdx.z == 1) ? W1
                   : (blockIdx.z == 2) ? W2 : W3;
    bf16* dst = Wt + (size_t)blockIdx.z * DD * DD;

    __shared__ float T[64][65];
    int k0 = blockIdx.y * 64, n0 = blockIdx.x * 64;
    int tr = threadIdx.x >> 4, tc = (threadIdx.x & 15) * 4;
#pragma unroll
    for (int u = 0; u < 4; u++) {
        int r = tr + u * 16;
        float4 v = *(const float4*)&W[(size_t)(k0 + r) * DD + n0 + tc];
        T[tc + 0][r] = v.x; T[tc + 1][r] = v.y;
        T[tc + 2][r] = v.z; T[tc + 3][r] = v.w;
    }
    __syncthreads();
#pragma unroll
    for (int u = 0; u < 4; u++) {
        int r = tr + u * 16;   // n index
        bf16x4 o;
        o[0] = (bf16)T[r][tc + 0]; o[1] = (bf16)T[r][tc + 1];
        o[2] = (bf16)T[r][tc + 2]; o[3] = (bf16)T[r][tc + 3];
        *(bf16x4*)&dst[(size_t)(n0 + r) * DD + k0 + tc] = o;
    }
}

// ---------------------------------------------------------------------------
// Prep 3: V [token][h*64+d] bf16 -> Vt_g [bh][d][s] bf16 (per-head transpose).
// grid (S/64=32, BH=32), 256 threads.
// ---------------------------------------------------------------------------
__global__ __launch_bounds__(256) void vt_kernel(const bf16* __restrict__ V,
                                                 bf16* __restrict__ Vt) {
    const int bh = blockIdx.y;
    const int b = bh >> 4, h = bh & 15;
    const int s0 = blockIdx.x * 64;

    __shared__ bf16 T[64][72];
    const int r = threadIdx.x >> 2;            // 0..63
    const int c0 = (threadIdx.x & 3) * 16;     // 0,16,32,48

    const bf16* src = V + ((size_t)(b * SS + s0 + r)) * DD + h * HD + c0;
    *(bf16x8*)&T[r][c0]     = *(const bf16x8*)(src);
    *(bf16x8*)&T[r][c0 + 8] = *(const bf16x8*)(src + 8);
    __syncthreads();

    bf16x8 o0, o1;
#pragma unroll
    for (int i = 0; i < 8; i++) o0[i] = T[c0 + i][r];
#pragma unroll
    for (int i = 0; i < 8; i++) o1[i] = T[c0 + 8 + i][r];
    bf16* dst = Vt + ((size_t)bh * HD + r) * SS + s0 + c0;
    *(bf16x8*)dst       = o0;
    *(bf16x8*)(dst + 8) = o1;
}

// ---------------------------------------------------------------------------
// MFMA GEMM (R3 form): C[m][n] = sum_k A[m][k] * Wt[n][k] + bias[n]
// 128x128 tile, BK=64, 256 threads (4 waves, each 64x64). XOR-swizzled LDS.
// z selects weight/bias/dst for QKV (z=0 output scaled by QSCL).
// ---------------------------------------------------------------------------
__global__ __launch_bounds__(256) void mfma_gemm(
    const bf16* __restrict__ A, const bf16* __restrict__ Wt0,
    const float* __restrict__ b0, const float* __restrict__ b1,
    const float* __restrict__ b2,
    bf16* __restrict__ o0, bf16* __restrict__ o1, bf16* __restrict__ o2) {
    const int z = blockIdx.z;
    const bf16* Wt = Wt0 + (size_t)z * DD * DD;
    const float* bias = (z == 0) ? b0 : (z == 1) ? b1 : b2;
    bf16* dstb = (z == 0) ? o0 : (z == 1) ? o1 : o2;
    const float scl = (z == 0) ? QSCL : 1.0f;

    __shared__ __align__(16) bf16 As[128 * 64];
    __shared__ __align__(16) bf16 Bs[128 * 64];

    const int tid = threadIdx.x;
    const int lane = tid & 63;
    const int w = tid >> 6;
    const int l15 = lane & 15, quad = lane >> 4;
    const int m0 = blockIdx.y * 128;
    const int n0 = blockIdx.x * 128;
    const int mw = (w & 1) * 64;
    const int nw = (w >> 1) * 64;

    f32x4 acc[4][4];
#pragma unroll
    for (int i = 0; i < 4; i++)
#pragma unroll
        for (int j = 0; j < 4; j++) acc[i][j] = (f32x4){0.f, 0.f, 0.f, 0.f};

    for (int kt = 0; kt < DD; kt += 64) {
        __syncthreads();
#pragma unroll
        for (int u = 0; u < 4; u++) {
            int j = tid + u * 256;          // chunk 0..1023
            int row = j >> 3, cp = j & 7;
            int c = cp ^ (row & 7);         // global 16B-chunk within row
            glds16(A  + (size_t)(m0 + row) * DD + kt + c * 8, &As[j * 8]);
            glds16(Wt + (size_t)(n0 + row) * DD + kt + c * 8, &Bs[j * 8]);
        }
        __syncthreads();

#pragma unroll
        for (int kh = 0; kh < 2; kh++) {
            bf16x8 af[4], bf[4];
#pragma unroll
            for (int i = 0; i < 4; i++) {
                int ra = mw + i * 16 + l15;
                int ja = ra * 8 + ((kh * 4 + quad) ^ (ra & 7));
                af[i] = *(const bf16x8*)&As[ja * 8];
                int rb = nw + i * 16 + l15;
                int jb = rb * 8 + ((kh * 4 + quad) ^ (rb & 7));
                bf[i] = *(const bf16x8*)&Bs[jb * 8];
            }
#pragma unroll
            for (int i = 0; i < 4; i++)
#pragma unroll
                for (int j = 0; j < 4; j++)
                    acc[i][j] = __builtin_amdgcn_mfma_f32_16x16x32_bf16(
                        af[i], bf[j], acc[i][j], 0, 0, 0);
        }
    }

    float bcol[4];
#pragma unroll
    for (int j = 0; j < 4; j++) bcol[j] = bias[n0 + nw + j * 16 + l15];

#pragma unroll
    for (int i = 0; i < 4; i++)
#pragma unroll
        for (int j = 0; j < 4; j++)
#pragma unroll
            for (int r = 0; r < 4; r++) {
                int row = m0 + mw + i * 16 + quad * 4 + r;
                int col = n0 + nw + j * 16 + l15;
                dstb[(size_t)row * DD + col] =
                    (bf16)((acc[i][j][r] + bcol[j]) * scl);
            }
}

// ---------------------------------------------------------------------------
// Out-proj GEMM: 64x128 tile (M x N), BK=64, 256 threads (4 waves, 32x64).
// grid (8, 64) = 512 blocks -> 2 blocks/CU (vs 1 for 128x128). fp32 output.
// ---------------------------------------------------------------------------
__global__ __launch_bounds__(256) void mfma_gemm_out(
    const bf16* __restrict__ A, const bf16* __restrict__ Wt,
    const float* __restrict__ bias, float* __restrict__ out) {
    __shared__ __align__(16) bf16 As[64 * 64];
    __shared__ __align__(16) bf16 Bs[128 * 64];

    const int tid = threadIdx.x;
    const int lane = tid & 63;
    const int w = tid >> 6;
    const int l15 = lane & 15, quad = lane >> 4;
    const int m0 = blockIdx.y * 64;
    const int n0 = blockIdx.x * 128;
    const int mw = (w & 1) * 32;
    const int nw = (w >> 1) * 64;

    f32x4 acc[2][4];
#pragma unroll
    for (int i = 0; i < 2; i++)
#pragma unroll
        for (int j = 0; j < 4; j++) acc[i][j] = (f32x4){0.f, 0.f, 0.f, 0.f};

    for (int kt = 0; kt < DD; kt += 64) {
        __syncthreads();
#pragma unroll
        for (int u = 0; u < 2; u++) {      // As: 512 chunks
            int j = tid + u * 256;
            int row = j >> 3, c = (j & 7) ^ (row & 7);
            glds16(A + (size_t)(m0 + row) * DD + kt + c * 8, &As[j * 8]);
        }
#pragma unroll
        for (int u = 0; u < 4; u++) {      // Bs: 1024 chunks
            int j = tid + u * 256;
            int row = j >> 3, c = (j & 7) ^ (row & 7);
            glds16(Wt + (size_t)(n0 + row) * DD + kt + c * 8, &Bs[j * 8]);
        }
        __syncthreads();

#pragma unroll
        for (int kh = 0; kh < 2; kh++) {
            bf16x8 af[2], bf[4];
#pragma unroll
            for (int i = 0; i < 2; i++) {
                int ra = mw + i * 16 + l15;
                int ja = ra * 8 + ((kh * 4 + quad) ^ (ra & 7));
                af[i] = *(const bf16x8*)&As[ja * 8];
            }
#pragma unroll
            for (int j = 0; j < 4; j++) {
                int rb = nw + j * 16 + l15;
                int jb = rb * 8 + ((kh * 4 + quad) ^ (rb & 7));
                bf[j] = *(const bf16x8*)&Bs[jb * 8];
            }
#pragma unroll
            for (int i = 0; i < 2; i++)
#pragma unroll
                for (int j = 0; j < 4; j++)
                    acc[i][j] = __builtin_amdgcn_mfma_f32_16x16x32_bf16(
                        af[i], bf[j], acc[i][j], 0, 0, 0);
        }
    }

    float bcol[4];
#pragma unroll
    for (int j = 0; j < 4; j++) bcol[j] = bias[n0 + nw + j * 16 + l15];

#pragma unroll
    for (int i = 0; i < 2; i++)
#pragma unroll
        for (int j = 0; j < 4; j++)
#pragma unroll
            for (int r = 0; r < 4; r++) {
                int row = m0 + mw + i * 16 + quad * 4 + r;
                int col = n0 + nw + j * 16 + l15;
                out[(size_t)row * DD + col] = acc[i][j][r] + bcol[j];
            }
}

// ---------------------------------------------------------------------------
// MFMA flash attention v2b (hardened sync):
//   * 2 waves/block (128 thr), 32 queries/wave, 64 q/block. grid (32,32).
//     -> every LDS K/V fragment read feeds 2 MFMAs (half the LDS read traffic
//        per query vs 16 q/wave).
//   * double-buffered K/V LDS (40 KB total -> 4 blocks/CU), 1-deep prefetch:
//     issue next tile's glds16 BEFORE compute; single __syncthreads() per tile
//     (compiler emits s_waitcnt vmcnt(0) lgkmcnt(0) + s_barrier). Load latency
//     hides under compute instead of stalling all waves.
//   * row-sum of P via MFMA with ones-B (output lane layout == o's), removing
//     the serial 16-add reduction + shuffles per tile AND the final shuffle.
//   * P f32->bf16 via packed v_cvt_pk_bf16_f32 (8 instead of 16 cvts/tile).
// Q pre-scaled by log2e/8; no-max softmax (exp2).
// ---------------------------------------------------------------------------
__global__ __launch_bounds__(128) void mfma_attn(
    const bf16* __restrict__ Qb, const bf16* __restrict__ Kb,
    const bf16* __restrict__ Vtg, bf16* __restrict__ ctxb) {
    __shared__ __align__(16) bf16 Ks[2][64 * 64];   // [buf][key][d] swizzled
    __shared__ __align__(16) bf16 Vs[2][64 * 64];   // [buf][d][key] swizzled
    __shared__ __align__(16) bf16 Ps[2][32 * 64];   // per-wave [q][key] swizzled

    const int tid = threadIdx.x;
    const int lane = tid & 63;
    const int w = tid >> 6;                  // 0..1
    const int l15 = lane & 15, quad = lane >> 4;
    const int bh = blockIdx.y;
    const int b = bh >> 4, h = bh & 15;
    const int q0 = blockIdx.x * 64;
    const size_t mb = (size_t)b * SS;
    const int hc = h * HD;
    const bf16* Vt_bh = Vtg + (size_t)bh * HD * SS;
    bf16* Pw = &Ps[w][0];

    // ---- Q fragments direct from global (held all kernel; B operand) ----
    bf16x8 qf[2][2];
#pragma unroll
    for (int qb = 0; qb < 2; qb++)
#pragma unroll
        for (int kh = 0; kh < 2; kh++)
            qf[qb][kh] = *(const bf16x8*)&Qb[(mb + q0 + w * 32 + qb * 16 + l15) * DD +
                                             hc + kh * 32 + quad * 8];

    // ones fragment for row-sum MFMA
    bf16x8 onev;
#pragma unroll
    for (int i = 0; i < 8; i++) onev[i] = (bf16)1.0f;

    // ---- hoisted loop-invariant LDS offsets (elements) ----
    int koff[4][2], voff[4][2], prd[2], pwr[4];
#pragma unroll
    for (int kb = 0; kb < 4; kb++) {
        int rk = kb * 16 + l15;
#pragma unroll
        for (int kh = 0; kh < 2; kh++)
            koff[kb][kh] = (rk * 8 + ((kh * 4 + quad) ^ (rk & 7))) * 8;
    }
#pragma unroll
    for (int nb = 0; nb < 4; nb++) {
        int rv = nb * 16 + l15;
#pragma unroll
        for (int kh = 0; kh < 2; kh++)
            voff[nb][kh] = (rv * 8 + ((kh * 4 + quad) ^ (rv & 7))) * 8;
    }
#pragma unroll
    for (int kh = 0; kh < 2; kh++)
        prd[kh] = l15 * 64 + (((kh * 4 + quad) ^ (l15 & 7)) << 3);
#pragma unroll
    for (int kb = 0; kb < 4; kb++) {
        int cw = kb * 2 + (quad >> 1);
        pwr[kb] = l15 * 64 + ((cw ^ (l15 & 7)) << 3) + (quad & 1) * 4;
    }

    // ---- staging pointers (4 chunks each of K and V per thread) ----
    const bf16* gK[4]; const bf16* gV[4]; int lo_[4];
#pragma unroll
    for (int u = 0; u < 4; u++) {
        int j = tid + u * 128;              // chunk 0..511
        int row = j >> 3, cp = j & 7;
        int c = cp ^ (row & 7);
        gK[u] = Kb + (mb + row) * DD + hc + c * 8;
        gV[u] = Vt_bh + (size_t)row * SS + c * 8;
        lo_[u] = j * 8;
    }

    f32x4 o[2][4], lsum[2];
#pragma unroll
    for (int qb = 0; qb < 2; qb++) {
        lsum[qb] = (f32x4){0.f, 0.f, 0.f, 0.f};
#pragma unroll
        for (int nb = 0; nb < 4; nb++) o[qb][nb] = (f32x4){0.f, 0.f, 0.f, 0.f};
    }

    // ---- prologue: stage tile 0 into buf 0 ----
#pragma unroll
    for (int u = 0; u < 4; u++) {
        glds16(gK[u], &Ks[0][lo_[u]]);  gK[u] += 64 * DD;
        glds16(gV[u], &Vs[0][lo_[u]]);  gV[u] += 64;
    }
    __syncthreads();

    for (int it = 0; it < SS / 64; ++it) {
        const int buf = it & 1;
        // ---- prefetch next tile into the other buffer (in flight over compute)
        if (it + 1 < SS / 64) {
#pragma unroll
            for (int u = 0; u < 4; u++) {
                glds16(gK[u], &Ks[buf ^ 1][lo_[u]]);  gK[u] += 64 * DD;
                glds16(gV[u], &Vs[buf ^ 1][lo_[u]]);  gV[u] += 64;
            }
        }

        // ---- scores: S^T tiles (A = K rows, B = Q); kf reused by both qb ----
        f32x4 sc[2][4];
#pragma unroll
        for (int qb = 0; qb < 2; qb++)
#pragma unroll
            for (int kb = 0; kb < 4; kb++) sc[qb][kb] = (f32x4){0.f, 0.f, 0.f, 0.f};
#pragma unroll
        for (int kb = 0; kb < 4; kb++)
#pragma unroll
            for (int kh = 0; kh < 2; kh++) {
                bf16x8 kf = *(const bf16x8*)&Ks[buf][koff[kb][kh]];
                sc[0][kb] = __builtin_amdgcn_mfma_f32_16x16x32_bf16(
                    kf, qf[0][kh], sc[0][kb], 0, 0, 0);
                sc[1][kb] = __builtin_amdgcn_mfma_f32_16x16x32_bf16(
                    kf, qf[1][kh], sc[1][kb], 0, 0, 0);
            }

        // ---- no-max softmax: p = exp2(score), packed cvt, store to Ps ----
#pragma unroll
        for (int qb = 0; qb < 2; qb++)
#pragma unroll
            for (int kb = 0; kb < 4; kb++) {
                float p0 = exp2f(sc[qb][kb][0]);
                float p1 = exp2f(sc[qb][kb][1]);
                float p2 = exp2f(sc[qb][kb][2]);
                float p3 = exp2f(sc[qb][kb][3]);
                uint2 pu;
                pu.x = cvtpk_bf16(p0, p1);
                pu.y = cvtpk_bf16(p2, p3);
                *(uint2*)&Pw[qb * 1024 + pwr[kb]] = pu;
            }

        // ---- PV + row-sum: A = P (m=q), B = V^T (k=key, n=d) / ones ----
#pragma unroll
        for (int kh = 0; kh < 2; kh++) {
            bf16x8 pf0 = *(const bf16x8*)&Pw[prd[kh]];
            bf16x8 pf1 = *(const bf16x8*)&Pw[1024 + prd[kh]];
            lsum[0] = __builtin_amdgcn_mfma_f32_16x16x32_bf16(
                pf0, onev, lsum[0], 0, 0, 0);
            lsum[1] = __builtin_amdgcn_mfma_f32_16x16x32_bf16(
                pf1, onev, lsum[1], 0, 0, 0);
#pragma unroll
            for (int nb = 0; nb < 4; nb++) {
                bf16x8 vf = *(const bf16x8*)&Vs[buf][voff[nb][kh]];
                o[0][nb] = __builtin_amdgcn_mfma_f32_16x16x32_bf16(
                    pf0, vf, o[0][nb], 0, 0, 0);
                o[1][nb] = __builtin_amdgcn_mfma_f32_16x16x32_bf16(
                    pf1, vf, o[1][nb], 0, 0, 0);
            }
        }

        // ---- tile boundary: prefetched loads landed; all waves done reading
        __syncthreads();
    }

    // ---- finalize: divide by row sum (lane layout matches o), store bf16 ----
#pragma unroll
    for (int qb = 0; qb < 2; qb++) {
        float li[4];
#pragma unroll
        for (int r = 0; r < 4; r++) li[r] = 1.0f / lsum[qb][r];
#pragma unroll
        for (int nb = 0; nb < 4; nb++)
#pragma unroll
            for (int r = 0; r < 4; r++) {
                int qrow = q0 + w * 32 + qb * 16 + quad * 4 + r;
                ctxb[(mb + qrow) * DD + hc + nb * 16 + l15] =
                    (bf16)(o[qb][nb][r] * li[r]);
            }
    }
}

// ---------------------------------------------------------------------------
extern "C" void kernel_launch(void* const* d_in, const int* in_sizes, int n_in,
                              void* d_out, int out_size, void* d_ws, size_t ws_size,
                              hipStream_t stream) {
    const float* x  = (const float*)d_in[0];
    const float* Wq = (const float*)d_in[1];
    const float* bq = (const float*)d_in[2];
    const float* Wk = (const float*)d_in[3];
    const float* bk = (const float*)d_in[4];
    const float* Wv = (const float*)d_in[5];
    const float* bv = (const float*)d_in[6];
    const float* Wo = (const float*)d_in[7];
    const float* bo = (const float*)d_in[8];
    float* out = (float*)d_out;

    char* base = (char*)d_ws;
    bf16* xb   = (bf16*)(base);                        //  8 MB (dead after QKV gemm)
    bf16* Wt   = (bf16*)(base + (8ull  << 20));        //  4 x 2 MB
    bf16* Qb   = (bf16*)(base + (16ull << 20));        //  8 MB (pre-scaled)
    bf16* Kb   = (bf16*)(base + (24ull << 20));        //  8 MB
    bf16* Vb   = (bf16*)(base + (32ull << 20));        //  8 MB
    bf16* ctxb = (bf16*)(base + (40ull << 20));        //  8 MB
    bf16* Vtg  = xb;                                   //  reuse xb region

    cvt_x<<<dim3((MM * DD) / (256 * 4)), dim3(256), 0, stream>>>(x, xb);
    cvt_w<<<dim3(16, 16, 4), dim3(256), 0, stream>>>(Wq, Wk, Wv, Wo, Wt);

    mfma_gemm<<<dim3(DD / 128, MM / 128, 3), dim3(256), 0, stream>>>(
        xb, Wt, bq, bk, bv, Qb, Kb, Vb);

    vt_kernel<<<dim3(SS / 64, BB * HH), dim3(256), 0, stream>>>(Vb, Vtg);

    mfma_attn<<<dim3(SS / 64, BB * HH), dim3(128), 0, stream>>>(Qb, Kb, Vtg, ctxb);

    mfma_gemm_out<<<dim3(DD / 128, MM / 64), dim3(256), 0, stream>>>(
        ctxb, Wt + 3ull * DD * DD, bo, out);
}

// Round 4
// 226.252 us; speedup vs baseline: 1.0300x; 1.0300x over previous
//
#include <hip/hip_runtime.h>
#include <hip/hip_bf16.h>
#include <math.h>

#define BB 2
#define SS 2048
#define DD 1024
#define HH 16
#define HD 64
#define MM (BB * SS)   // 4096

typedef __bf16 bf16;
typedef __attribute__((ext_vector_type(8))) __bf16 bf16x8;
typedef __attribute__((ext_vector_type(4))) __bf16 bf16x4;
typedef __attribute__((ext_vector_type(4))) float f32x4;

#define QSCL 0.18033688011112042f   // log2(e)/8, folded into Q at projection

// async global->LDS, 16B per lane. LDS dest must be wave-uniform base + lane*16.
__device__ __forceinline__ void glds16(const bf16* g, bf16* l) {
    __builtin_amdgcn_global_load_lds(
        (const __attribute__((address_space(1))) void*)g,
        (__attribute__((address_space(3))) void*)l, 16, 0, 0);
}

// packed f32x2 -> bf16x2 (no builtin on gfx950; T12 primitive)
__device__ __forceinline__ unsigned cvtpk_bf16(float a, float b) {
    unsigned r;
    asm("v_cvt_pk_bf16_f32 %0, %1, %2" : "=v"(r) : "v"(a), "v"(b));
    return r;
}

// ---------------------------------------------------------------------------
// Prep 1: x (fp32) -> xb (bf16).  4M elements, 4/thread.
// ---------------------------------------------------------------------------
__global__ __launch_bounds__(256) void cvt_x(const float* __restrict__ x,
                                             bf16* __restrict__ xb) {
    int i = (blockIdx.x * 256 + threadIdx.x) * 4;
    float4 v = *(const float4*)(x + i);
    bf16x4 o;
    o[0] = (bf16)v.x; o[1] = (bf16)v.y; o[2] = (bf16)v.z; o[3] = (bf16)v.w;
    *(bf16x4*)(xb + i) = o;
}

// ---------------------------------------------------------------------------
// Prep 2: W[k][n] fp32 -> Wt[n][k] bf16 (4 weights via z). 64x64 LDS transpose.
// ---------------------------------------------------------------------------
__global__ __launch_bounds__(256) void cvt_w(
    const float* __restrict__ W0, const float* __restrict__ W1,
    const float* __restrict__ W2, const float* __restrict__ W3,
    bf16* __restrict__ Wt) {
    const float* W = (blockIdx.z == 0) ? W0 : (blockIdx.z == 1) ? W1
                   : (blockIdx.z == 2) ? W2 : W3;
    bf16* dst = Wt + (size_t)blockIdx.z * DD * DD;

    __shared__ float T[64][65];
    int k0 = blockIdx.y * 64, n0 = blockIdx.x * 64;
    int tr = threadIdx.x >> 4, tc = (threadIdx.x & 15) * 4;
#pragma unroll
    for (int u = 0; u < 4; u++) {
        int r = tr + u * 16;
        float4 v = *(const float4*)&W[(size_t)(k0 + r) * DD + n0 + tc];
        T[tc + 0][r] = v.x; T[tc + 1][r] = v.y;
        T[tc + 2][r] = v.z; T[tc + 3][r] = v.w;
    }
    __syncthreads();
#pragma unroll
    for (int u = 0; u < 4; u++) {
        int r = tr + u * 16;   // n index
        bf16x4 o;
        o[0] = (bf16)T[r][tc + 0]; o[1] = (bf16)T[r][tc + 1];
        o[2] = (bf16)T[r][tc + 2]; o[3] = (bf16)T[r][tc + 3];
        *(bf16x4*)&dst[(size_t)(n0 + r) * DD + k0 + tc] = o;
    }
}

// ---------------------------------------------------------------------------
// Prep 3: V [token][h*64+d] bf16 -> Vt_g [bh][d][s] bf16 (per-head transpose).
// grid (S/64=32, BH=32), 256 threads.
// ---------------------------------------------------------------------------
__global__ __launch_bounds__(256) void vt_kernel(const bf16* __restrict__ V,
                                                 bf16* __restrict__ Vt) {
    const int bh = blockIdx.y;
    const int b = bh >> 4, h = bh & 15;
    const int s0 = blockIdx.x * 64;

    __shared__ bf16 T[64][72];
    const int r = threadIdx.x >> 2;            // 0..63
    const int c0 = (threadIdx.x & 3) * 16;     // 0,16,32,48

    const bf16* src = V + ((size_t)(b * SS + s0 + r)) * DD + h * HD + c0;
    *(bf16x8*)&T[r][c0]     = *(const bf16x8*)(src);
    *(bf16x8*)&T[r][c0 + 8] = *(const bf16x8*)(src + 8);
    __syncthreads();

    bf16x8 o0, o1;
#pragma unroll
    for (int i = 0; i < 8; i++) o0[i] = T[c0 + i][r];
#pragma unroll
    for (int i = 0; i < 8; i++) o1[i] = T[c0 + 8 + i][r];
    bf16* dst = Vt + ((size_t)bh * HD + r) * SS + s0 + c0;
    *(bf16x8*)dst       = o0;
    *(bf16x8*)(dst + 8) = o1;
}

// ---------------------------------------------------------------------------
// MFMA GEMM (R3 form): C[m][n] = sum_k A[m][k] * Wt[n][k] + bias[n]
// 128x128 tile, BK=64, 256 threads (4 waves, each 64x64). XOR-swizzled LDS.
// z selects weight/bias/dst for QKV (z=0 output scaled by QSCL).
// ---------------------------------------------------------------------------
__global__ __launch_bounds__(256) void mfma_gemm(
    const bf16* __restrict__ A, const bf16* __restrict__ Wt0,
    const float* __restrict__ b0, const float* __restrict__ b1,
    const float* __restrict__ b2,
    bf16* __restrict__ o0, bf16* __restrict__ o1, bf16* __restrict__ o2) {
    const int z = blockIdx.z;
    const bf16* Wt = Wt0 + (size_t)z * DD * DD;
    const float* bias = (z == 0) ? b0 : (z == 1) ? b1 : b2;
    bf16* dstb = (z == 0) ? o0 : (z == 1) ? o1 : o2;
    const float scl = (z == 0) ? QSCL : 1.0f;

    __shared__ __align__(16) bf16 As[128 * 64];
    __shared__ __align__(16) bf16 Bs[128 * 64];

    const int tid = threadIdx.x;
    const int lane = tid & 63;
    const int w = tid >> 6;
    const int l15 = lane & 15, quad = lane >> 4;
    const int m0 = blockIdx.y * 128;
    const int n0 = blockIdx.x * 128;
    const int mw = (w & 1) * 64;
    const int nw = (w >> 1) * 64;

    f32x4 acc[4][4];
#pragma unroll
    for (int i = 0; i < 4; i++)
#pragma unroll
        for (int j = 0; j < 4; j++) acc[i][j] = (f32x4){0.f, 0.f, 0.f, 0.f};

    for (int kt = 0; kt < DD; kt += 64) {
        __syncthreads();
#pragma unroll
        for (int u = 0; u < 4; u++) {
            int j = tid + u * 256;          // chunk 0..1023
            int row = j >> 3, cp = j & 7;
            int c = cp ^ (row & 7);         // global 16B-chunk within row
            glds16(A  + (size_t)(m0 + row) * DD + kt + c * 8, &As[j * 8]);
            glds16(Wt + (size_t)(n0 + row) * DD + kt + c * 8, &Bs[j * 8]);
        }
        __syncthreads();

#pragma unroll
        for (int kh = 0; kh < 2; kh++) {
            bf16x8 af[4], bf[4];
#pragma unroll
            for (int i = 0; i < 4; i++) {
                int ra = mw + i * 16 + l15;
                int ja = ra * 8 + ((kh * 4 + quad) ^ (ra & 7));
                af[i] = *(const bf16x8*)&As[ja * 8];
                int rb = nw + i * 16 + l15;
                int jb = rb * 8 + ((kh * 4 + quad) ^ (rb & 7));
                bf[i] = *(const bf16x8*)&Bs[jb * 8];
            }
#pragma unroll
            for (int i = 0; i < 4; i++)
#pragma unroll
                for (int j = 0; j < 4; j++)
                    acc[i][j] = __builtin_amdgcn_mfma_f32_16x16x32_bf16(
                        af[i], bf[j], acc[i][j], 0, 0, 0);
        }
    }

    float bcol[4];
#pragma unroll
    for (int j = 0; j < 4; j++) bcol[j] = bias[n0 + nw + j * 16 + l15];

#pragma unroll
    for (int i = 0; i < 4; i++)
#pragma unroll
        for (int j = 0; j < 4; j++)
#pragma unroll
            for (int r = 0; r < 4; r++) {
                int row = m0 + mw + i * 16 + quad * 4 + r;
                int col = n0 + nw + j * 16 + l15;
                dstb[(size_t)row * DD + col] =
                    (bf16)((acc[i][j][r] + bcol[j]) * scl);
            }
}

// ---------------------------------------------------------------------------
// Out-proj GEMM: 64x128 tile (M x N), BK=64, 256 threads (4 waves, 32x64).
// grid (8, 64) = 512 blocks -> 2 blocks/CU (vs 1 for 128x128). fp32 output.
// ---------------------------------------------------------------------------
__global__ __launch_bounds__(256) void mfma_gemm_out(
    const bf16* __restrict__ A, const bf16* __restrict__ Wt,
    const float* __restrict__ bias, float* __restrict__ out) {
    __shared__ __align__(16) bf16 As[64 * 64];
    __shared__ __align__(16) bf16 Bs[128 * 64];

    const int tid = threadIdx.x;
    const int lane = tid & 63;
    const int w = tid >> 6;
    const int l15 = lane & 15, quad = lane >> 4;
    const int m0 = blockIdx.y * 64;
    const int n0 = blockIdx.x * 128;
    const int mw = (w & 1) * 32;
    const int nw = (w >> 1) * 64;

    f32x4 acc[2][4];
#pragma unroll
    for (int i = 0; i < 2; i++)
#pragma unroll
        for (int j = 0; j < 4; j++) acc[i][j] = (f32x4){0.f, 0.f, 0.f, 0.f};

    for (int kt = 0; kt < DD; kt += 64) {
        __syncthreads();
#pragma unroll
        for (int u = 0; u < 2; u++) {      // As: 512 chunks
            int j = tid + u * 256;
            int row = j >> 3, c = (j & 7) ^ (row & 7);
            glds16(A + (size_t)(m0 + row) * DD + kt + c * 8, &As[j * 8]);
        }
#pragma unroll
        for (int u = 0; u < 4; u++) {      // Bs: 1024 chunks
            int j = tid + u * 256;
            int row = j >> 3, c = (j & 7) ^ (row & 7);
            glds16(Wt + (size_t)(n0 + row) * DD + kt + c * 8, &Bs[j * 8]);
        }
        __syncthreads();

#pragma unroll
        for (int kh = 0; kh < 2; kh++) {
            bf16x8 af[2], bf[4];
#pragma unroll
            for (int i = 0; i < 2; i++) {
                int ra = mw + i * 16 + l15;
                int ja = ra * 8 + ((kh * 4 + quad) ^ (ra & 7));
                af[i] = *(const bf16x8*)&As[ja * 8];
            }
#pragma unroll
            for (int j = 0; j < 4; j++) {
                int rb = nw + j * 16 + l15;
                int jb = rb * 8 + ((kh * 4 + quad) ^ (rb & 7));
                bf[j] = *(const bf16x8*)&Bs[jb * 8];
            }
#pragma unroll
            for (int i = 0; i < 2; i++)
#pragma unroll
                for (int j = 0; j < 4; j++)
                    acc[i][j] = __builtin_amdgcn_mfma_f32_16x16x32_bf16(
                        af[i], bf[j], acc[i][j], 0, 0, 0);
        }
    }

    float bcol[4];
#pragma unroll
    for (int j = 0; j < 4; j++) bcol[j] = bias[n0 + nw + j * 16 + l15];

#pragma unroll
    for (int i = 0; i < 2; i++)
#pragma unroll
        for (int j = 0; j < 4; j++)
#pragma unroll
            for (int r = 0; r < 4; r++) {
                int row = m0 + mw + i * 16 + quad * 4 + r;
                int col = n0 + nw + j * 16 + l15;
                out[(size_t)row * DD + col] = acc[i][j][r] + bcol[j];
            }
}

// ---------------------------------------------------------------------------
// MFMA flash attention v3b: round-0 structure (4 waves x 16 q/wave, 256 thr,
// 4 blocks/CU) + validated improvements only:
//   * double-buffered K/V LDS (40 KB -> still 4 blocks/CU), 1-deep prefetch:
//     next tile's glds16 issued BEFORE compute, one __syncthreads()/tile.
//   * row-sum of P via MFMA with ones-B (lane layout == o's): kills the
//     serial 16-add reduction + 2 shuffles per tile + final shuffle fix-up.
//   * P f32->bf16 via packed v_cvt_pk_bf16_f32.
//   * exp2 via libm exp2f — NOT the raw v_exp_f32 builtin (round-3 failure:
//     absmax 1.89e-3 > 1.56e-3; the builtin's error is too large here).
// Q pre-scaled by log2e/8; no-max softmax (exp2).
// ---------------------------------------------------------------------------
__global__ __launch_bounds__(256) void mfma_attn(
    const bf16* __restrict__ Qb, const bf16* __restrict__ Kb,
    const bf16* __restrict__ Vtg, bf16* __restrict__ ctxb) {
    __shared__ __align__(16) bf16 Ks[2][64 * 64];   // [buf][key][d] swizzled
    __shared__ __align__(16) bf16 Vs[2][64 * 64];   // [buf][d][key] swizzled
    __shared__ __align__(16) bf16 Ps[4][16 * 64];   // per-wave [q][key] swizzled

    const int tid = threadIdx.x;
    const int lane = tid & 63;
    const int w = tid >> 6;                  // 0..3
    const int l15 = lane & 15, quad = lane >> 4;
    const int bh = blockIdx.y;
    const int b = bh >> 4, h = bh & 15;
    const int q0 = blockIdx.x * 64;
    const size_t mb = (size_t)b * SS;
    const int hc = h * HD;
    const bf16* Vt_bh = Vtg + (size_t)bh * HD * SS;
    bf16* Pw = &Ps[w][0];

    // ---- Q fragments direct from global (held all kernel; B operand) ----
    bf16x8 qf[2];
#pragma unroll
    for (int kh = 0; kh < 2; kh++)
        qf[kh] = *(const bf16x8*)&Qb[(mb + q0 + w * 16 + l15) * DD +
                                     hc + kh * 32 + quad * 8];

    // ones fragment for row-sum MFMA
    bf16x8 onev;
#pragma unroll
    for (int i = 0; i < 8; i++) onev[i] = (bf16)1.0f;

    // ---- hoisted loop-invariant LDS offsets (elements) ----
    int koff[4][2], voff[4][2], prd[2], pwr[4];
#pragma unroll
    for (int kb = 0; kb < 4; kb++) {
        int rk = kb * 16 + l15;
#pragma unroll
        for (int kh = 0; kh < 2; kh++)
            koff[kb][kh] = (rk * 8 + ((kh * 4 + quad) ^ (rk & 7))) * 8;
    }
#pragma unroll
    for (int nb = 0; nb < 4; nb++) {
        int rv = nb * 16 + l15;
#pragma unroll
        for (int kh = 0; kh < 2; kh++)
            voff[nb][kh] = (rv * 8 + ((kh * 4 + quad) ^ (rv & 7))) * 8;
    }
#pragma unroll
    for (int kh = 0; kh < 2; kh++)
        prd[kh] = l15 * 64 + (((kh * 4 + quad) ^ (l15 & 7)) << 3);
#pragma unroll
    for (int kb = 0; kb < 4; kb++) {
        int cw = kb * 2 + (quad >> 1);
        pwr[kb] = l15 * 64 + ((cw ^ (l15 & 7)) << 3) + (quad & 1) * 4;
    }

    // ---- staging pointers (2 chunks each of K and V per thread) ----
    const bf16* gK[2]; const bf16* gV[2]; int lo_[2];
#pragma unroll
    for (int u = 0; u < 2; u++) {
        int j = tid + u * 256;              // chunk 0..511
        int row = j >> 3, cp = j & 7;
        int c = cp ^ (row & 7);
        gK[u] = Kb + (mb + row) * DD + hc + c * 8;
        gV[u] = Vt_bh + (size_t)row * SS + c * 8;
        lo_[u] = j * 8;
    }

    f32x4 o[4], lsum;
    lsum = (f32x4){0.f, 0.f, 0.f, 0.f};
#pragma unroll
    for (int nb = 0; nb < 4; nb++) o[nb] = (f32x4){0.f, 0.f, 0.f, 0.f};

    // ---- prologue: stage tile 0 into buf 0 ----
#pragma unroll
    for (int u = 0; u < 2; u++) {
        glds16(gK[u], &Ks[0][lo_[u]]);  gK[u] += 64 * DD;
        glds16(gV[u], &Vs[0][lo_[u]]);  gV[u] += 64;
    }
    __syncthreads();

    for (int it = 0; it < SS / 64; ++it) {
        const int buf = it & 1;
        // ---- prefetch next tile into the other buffer (in flight over compute)
        if (it + 1 < SS / 64) {
#pragma unroll
            for (int u = 0; u < 2; u++) {
                glds16(gK[u], &Ks[buf ^ 1][lo_[u]]);  gK[u] += 64 * DD;
                glds16(gV[u], &Vs[buf ^ 1][lo_[u]]);  gV[u] += 64;
            }
        }

        // ---- scores: S^T tiles (A = K rows, B = Q) ----
        f32x4 sc[4];
#pragma unroll
        for (int kb = 0; kb < 4; kb++) sc[kb] = (f32x4){0.f, 0.f, 0.f, 0.f};
#pragma unroll
        for (int kb = 0; kb < 4; kb++)
#pragma unroll
            for (int kh = 0; kh < 2; kh++) {
                bf16x8 kf = *(const bf16x8*)&Ks[buf][koff[kb][kh]];
                sc[kb] = __builtin_amdgcn_mfma_f32_16x16x32_bf16(
                    kf, qf[kh], sc[kb], 0, 0, 0);
            }

        // ---- no-max softmax: p = exp2(score) (libm exp2f), packed cvt ----
#pragma unroll
        for (int kb = 0; kb < 4; kb++) {
            float p0 = exp2f(sc[kb][0]);
            float p1 = exp2f(sc[kb][1]);
            float p2 = exp2f(sc[kb][2]);
            float p3 = exp2f(sc[kb][3]);
            uint2 pu;
            pu.x = cvtpk_bf16(p0, p1);
            pu.y = cvtpk_bf16(p2, p3);
            *(uint2*)&Pw[pwr[kb]] = pu;
        }

        // ---- PV + row-sum: A = P (m=q), B = V^T (k=key, n=d) / ones ----
#pragma unroll
        for (int kh = 0; kh < 2; kh++) {
            bf16x8 pf = *(const bf16x8*)&Pw[prd[kh]];
            lsum = __builtin_amdgcn_mfma_f32_16x16x32_bf16(
                pf, onev, lsum, 0, 0, 0);
#pragma unroll
            for (int nb = 0; nb < 4; nb++) {
                bf16x8 vf = *(const bf16x8*)&Vs[buf][voff[nb][kh]];
                o[nb] = __builtin_amdgcn_mfma_f32_16x16x32_bf16(
                    pf, vf, o[nb], 0, 0, 0);
            }
        }

        // ---- tile boundary: prefetched loads landed; all waves done reading
        __syncthreads();
    }

    // ---- finalize: divide by row sum (lane layout matches o), store bf16 ----
    float li[4];
#pragma unroll
    for (int r = 0; r < 4; r++) li[r] = 1.0f / lsum[r];
#pragma unroll
    for (int nb = 0; nb < 4; nb++)
#pragma unroll
        for (int r = 0; r < 4; r++) {
            int qrow = q0 + w * 16 + quad * 4 + r;
            ctxb[(mb + qrow) * DD + hc + nb * 16 + l15] =
                (bf16)(o[nb][r] * li[r]);
        }
}

// ---------------------------------------------------------------------------
extern "C" void kernel_launch(void* const* d_in, const int* in_sizes, int n_in,
                              void* d_out, int out_size, void* d_ws, size_t ws_size,
                              hipStream_t stream) {
    const float* x  = (const float*)d_in[0];
    const float* Wq = (const float*)d_in[1];
    const float* bq = (const float*)d_in[2];
    const float* Wk = (const float*)d_in[3];
    const float* bk = (const float*)d_in[4];
    const float* Wv = (const float*)d_in[5];
    const float* bv = (const float*)d_in[6];
    const float* Wo = (const float*)d_in[7];
    const float* bo = (const float*)d_in[8];
    float* out = (float*)d_out;

    char* base = (char*)d_ws;
    bf16* xb   = (bf16*)(base);                        //  8 MB (dead after QKV gemm)
    bf16* Wt   = (bf16*)(base + (8ull  << 20));        //  4 x 2 MB
    bf16* Qb   = (bf16*)(base + (16ull << 20));        //  8 MB (pre-scaled)
    bf16* Kb   = (bf16*)(base + (24ull << 20));        //  8 MB
    bf16* Vb   = (bf16*)(base + (32ull << 20));        //  8 MB
    bf16* ctxb = (bf16*)(base + (40ull << 20));        //  8 MB
    bf16* Vtg  = xb;                                   //  reuse xb region

    cvt_x<<<dim3((MM * DD) / (256 * 4)), dim3(256), 0, stream>>>(x, xb);
    cvt_w<<<dim3(16, 16, 4), dim3(256), 0, stream>>>(Wq, Wk, Wv, Wo, Wt);

    mfma_gemm<<<dim3(DD / 128, MM / 128, 3), dim3(256), 0, stream>>>(
        xb, Wt, bq, bk, bv, Qb, Kb, Vb);

    vt_kernel<<<dim3(SS / 64, BB * HH), dim3(256), 0, stream>>>(Vb, Vtg);

    mfma_attn<<<dim3(SS / 64, BB * HH), dim3(256), 0, stream>>>(Qb, Kb, Vtg, ctxb);

    mfma_gemm_out<<<dim3(DD / 128, MM / 64), dim3(256), 0, stream>>>(
        ctxb, Wt + 3ull * DD * DD, bo, out);
}

// Round 5
// 222.793 us; speedup vs baseline: 1.0460x; 1.0155x over previous
//
#include <hip/hip_runtime.h>
#include <hip/hip_bf16.h>
#include <math.h>

#define BB 2
#define SS 2048
#define DD 1024
#define HH 16
#define HD 64
#define MM (BB * SS)   // 4096

typedef __bf16 bf16;
typedef __attribute__((ext_vector_type(8))) __bf16 bf16x8;
typedef __attribute__((ext_vector_type(4))) __bf16 bf16x4;
typedef __attribute__((ext_vector_type(4))) float f32x4;
typedef __attribute__((ext_vector_type(4))) unsigned u32x4;

#define QSCL 0.18033688011112042f   // log2(e)/8, folded into Q at projection

// async global->LDS, 16B per lane. LDS dest must be wave-uniform base + lane*16.
__device__ __forceinline__ void glds16(const bf16* g, bf16* l) {
    __builtin_amdgcn_global_load_lds(
        (const __attribute__((address_space(1))) void*)g,
        (__attribute__((address_space(3))) void*)l, 16, 0, 0);
}

// packed f32x2 -> bf16x2 (no builtin on gfx950; T12 primitive)
__device__ __forceinline__ unsigned cvtpk_bf16(float a, float b) {
    unsigned r;
    asm("v_cvt_pk_bf16_f32 %0, %1, %2" : "=v"(r) : "v"(a), "v"(b));
    return r;
}

// ---------------------------------------------------------------------------
// Prep 1: x (fp32) -> xb (bf16).  4M elements, 4/thread.
// ---------------------------------------------------------------------------
__global__ __launch_bounds__(256) void cvt_x(const float* __restrict__ x,
                                             bf16* __restrict__ xb) {
    int i = (blockIdx.x * 256 + threadIdx.x) * 4;
    float4 v = *(const float4*)(x + i);
    bf16x4 o;
    o[0] = (bf16)v.x; o[1] = (bf16)v.y; o[2] = (bf16)v.z; o[3] = (bf16)v.w;
    *(bf16x4*)(xb + i) = o;
}

// ---------------------------------------------------------------------------
// Prep 2: W[k][n] fp32 -> Wt[n][k] bf16 (4 weights via z). 64x64 LDS transpose.
// ---------------------------------------------------------------------------
__global__ __launch_bounds__(256) void cvt_w(
    const float* __restrict__ W0, const float* __restrict__ W1,
    const float* __restrict__ W2, const float* __restrict__ W3,
    bf16* __restrict__ Wt) {
    const float* W = (blockIdx.z == 0) ? W0 : (blockIdx.z == 1) ? W1
                   : (blockIdx.z == 2) ? W2 : W3;
    bf16* dst = Wt + (size_t)blockIdx.z * DD * DD;

    __shared__ float T[64][65];
    int k0 = blockIdx.y * 64, n0 = blockIdx.x * 64;
    int tr = threadIdx.x >> 4, tc = (threadIdx.x & 15) * 4;
#pragma unroll
    for (int u = 0; u < 4; u++) {
        int r = tr + u * 16;
        float4 v = *(const float4*)&W[(size_t)(k0 + r) * DD + n0 + tc];
        T[tc + 0][r] = v.x; T[tc + 1][r] = v.y;
        T[tc + 2][r] = v.z; T[tc + 3][r] = v.w;
    }
    __syncthreads();
#pragma unroll
    for (int u = 0; u < 4; u++) {
        int r = tr + u * 16;   // n index
        bf16x4 o;
        o[0] = (bf16)T[r][tc + 0]; o[1] = (bf16)T[r][tc + 1];
        o[2] = (bf16)T[r][tc + 2]; o[3] = (bf16)T[r][tc + 3];
        *(bf16x4*)&dst[(size_t)(n0 + r) * DD + k0 + tc] = o;
    }
}

// ---------------------------------------------------------------------------
// Prep 3: V [token][h*64+d] bf16 -> Vt_g [bh][d][s'] bf16, with the key axis
// BIT-PERMUTED within each 64-token tile:  token m = [b5 b4 b3 b2 b1 b0]
// lands at column f(m) = [b5][b3 b2][b4][b1 b0].
// This makes the attention QK^T output fragment layout IDENTICAL to the PV
// A-operand fragment layout, so P never touches LDS (see mfma_attn).
// Read side of the transpose is permuted; 16B stores stay coalesced.
// grid (S/64=32, BH=32), 256 threads.
// ---------------------------------------------------------------------------
__global__ __launch_bounds__(256) void vt_kernel(const bf16* __restrict__ V,
                                                 bf16* __restrict__ Vt) {
    const int bh = blockIdx.y;
    const int b = bh >> 4, h = bh & 15;
    const int s0 = blockIdx.x * 64;

    __shared__ bf16 T[64][72];
    const int r = threadIdx.x >> 2;            // 0..63
    const int C = threadIdx.x & 3;             // 0..3
    const int c0 = C * 16;                     // d-offset for load phase

    const bf16* src = V + ((size_t)(b * SS + s0 + r)) * DD + h * HD + c0;
    *(bf16x8*)&T[r][c0]     = *(const bf16x8*)(src);
    *(bf16x8*)&T[r][c0 + 8] = *(const bf16x8*)(src + 8);
    __syncthreads();

    // write phase: thread handles d = r, output columns C*16 .. C*16+15.
    // output column v (within tile) holds token m = f^{-1}(C*16+v):
    //   M0 = (C>>1)*32 + (C&1)*8
    //   v 0-3 -> M0+v | v 4-7 -> M0+16+(v-4) | v 8-11 -> M0+4+(v-8)
    //   v 12-15 -> M0+20+(v-12)
    const int M0 = (C >> 1) * 32 + (C & 1) * 8;
    bf16x8 o0, o1;
#pragma unroll
    for (int i = 0; i < 4; i++) o0[i]     = T[M0 + i][r];
#pragma unroll
    for (int i = 0; i < 4; i++) o0[4 + i] = T[M0 + 16 + i][r];
#pragma unroll
    for (int i = 0; i < 4; i++) o1[i]     = T[M0 + 4 + i][r];
#pragma unroll
    for (int i = 0; i < 4; i++) o1[4 + i] = T[M0 + 20 + i][r];
    bf16* dst = Vt + ((size_t)bh * HD + r) * SS + s0 + c0;
    *(bf16x8*)dst       = o0;
    *(bf16x8*)(dst + 8) = o1;
}

// ---------------------------------------------------------------------------
// MFMA GEMM (R3 form): C[m][n] = sum_k A[m][k] * Wt[n][k] + bias[n]
// 128x128 tile, BK=64, 256 threads (4 waves, each 64x64). XOR-swizzled LDS.
// z selects weight/bias/dst for QKV (z=0 output scaled by QSCL).
// ---------------------------------------------------------------------------
__global__ __launch_bounds__(256) void mfma_gemm(
    const bf16* __restrict__ A, const bf16* __restrict__ Wt0,
    const float* __restrict__ b0, const float* __restrict__ b1,
    const float* __restrict__ b2,
    bf16* __restrict__ o0, bf16* __restrict__ o1, bf16* __restrict__ o2) {
    const int z = blockIdx.z;
    const bf16* Wt = Wt0 + (size_t)z * DD * DD;
    const float* bias = (z == 0) ? b0 : (z == 1) ? b1 : b2;
    bf16* dstb = (z == 0) ? o0 : (z == 1) ? o1 : o2;
    const float scl = (z == 0) ? QSCL : 1.0f;

    __shared__ __align__(16) bf16 As[128 * 64];
    __shared__ __align__(16) bf16 Bs[128 * 64];

    const int tid = threadIdx.x;
    const int lane = tid & 63;
    const int w = tid >> 6;
    const int l15 = lane & 15, quad = lane >> 4;
    const int m0 = blockIdx.y * 128;
    const int n0 = blockIdx.x * 128;
    const int mw = (w & 1) * 64;
    const int nw = (w >> 1) * 64;

    f32x4 acc[4][4];
#pragma unroll
    for (int i = 0; i < 4; i++)
#pragma unroll
        for (int j = 0; j < 4; j++) acc[i][j] = (f32x4){0.f, 0.f, 0.f, 0.f};

    for (int kt = 0; kt < DD; kt += 64) {
        __syncthreads();
#pragma unroll
        for (int u = 0; u < 4; u++) {
            int j = tid + u * 256;          // chunk 0..1023
            int row = j >> 3, cp = j & 7;
            int c = cp ^ (row & 7);         // global 16B-chunk within row
            glds16(A  + (size_t)(m0 + row) * DD + kt + c * 8, &As[j * 8]);
            glds16(Wt + (size_t)(n0 + row) * DD + kt + c * 8, &Bs[j * 8]);
        }
        __syncthreads();

#pragma unroll
        for (int kh = 0; kh < 2; kh++) {
            bf16x8 af[4], bf[4];
#pragma unroll
            for (int i = 0; i < 4; i++) {
                int ra = mw + i * 16 + l15;
                int ja = ra * 8 + ((kh * 4 + quad) ^ (ra & 7));
                af[i] = *(const bf16x8*)&As[ja * 8];
                int rb = nw + i * 16 + l15;
                int jb = rb * 8 + ((kh * 4 + quad) ^ (rb & 7));
                bf[i] = *(const bf16x8*)&Bs[jb * 8];
            }
#pragma unroll
            for (int i = 0; i < 4; i++)
#pragma unroll
                for (int j = 0; j < 4; j++)
                    acc[i][j] = __builtin_amdgcn_mfma_f32_16x16x32_bf16(
                        af[i], bf[j], acc[i][j], 0, 0, 0);
        }
    }

    float bcol[4];
#pragma unroll
    for (int j = 0; j < 4; j++) bcol[j] = bias[n0 + nw + j * 16 + l15];

#pragma unroll
    for (int i = 0; i < 4; i++)
#pragma unroll
        for (int j = 0; j < 4; j++)
#pragma unroll
            for (int r = 0; r < 4; r++) {
                int row = m0 + mw + i * 16 + quad * 4 + r;
                int col = n0 + nw + j * 16 + l15;
                dstb[(size_t)row * DD + col] =
                    (bf16)((acc[i][j][r] + bcol[j]) * scl);
            }
}

// ---------------------------------------------------------------------------
// Out-proj GEMM: 64x128 tile (M x N), BK=64, 256 threads (4 waves, 32x64).
// grid (8, 64) = 512 blocks -> 2 blocks/CU (vs 1 for 128x128). fp32 output.
// ---------------------------------------------------------------------------
__global__ __launch_bounds__(256) void mfma_gemm_out(
    const bf16* __restrict__ A, const bf16* __restrict__ Wt,
    const float* __restrict__ bias, float* __restrict__ out) {
    __shared__ __align__(16) bf16 As[64 * 64];
    __shared__ __align__(16) bf16 Bs[128 * 64];

    const int tid = threadIdx.x;
    const int lane = tid & 63;
    const int w = tid >> 6;
    const int l15 = lane & 15, quad = lane >> 4;
    const int m0 = blockIdx.y * 64;
    const int n0 = blockIdx.x * 128;
    const int mw = (w & 1) * 32;
    const int nw = (w >> 1) * 64;

    f32x4 acc[2][4];
#pragma unroll
    for (int i = 0; i < 2; i++)
#pragma unroll
        for (int j = 0; j < 4; j++) acc[i][j] = (f32x4){0.f, 0.f, 0.f, 0.f};

    for (int kt = 0; kt < DD; kt += 64) {
        __syncthreads();
#pragma unroll
        for (int u = 0; u < 2; u++) {      // As: 512 chunks
            int j = tid + u * 256;
            int row = j >> 3, c = (j & 7) ^ (row & 7);
            glds16(A + (size_t)(m0 + row) * DD + kt + c * 8, &As[j * 8]);
        }
#pragma unroll
        for (int u = 0; u < 4; u++) {      // Bs: 1024 chunks
            int j = tid + u * 256;
            int row = j >> 3, c = (j & 7) ^ (row & 7);
            glds16(Wt + (size_t)(n0 + row) * DD + kt + c * 8, &Bs[j * 8]);
        }
        __syncthreads();

#pragma unroll
        for (int kh = 0; kh < 2; kh++) {
            bf16x8 af[2], bf[4];
#pragma unroll
            for (int i = 0; i < 2; i++) {
                int ra = mw + i * 16 + l15;
                int ja = ra * 8 + ((kh * 4 + quad) ^ (ra & 7));
                af[i] = *(const bf16x8*)&As[ja * 8];
            }
#pragma unroll
            for (int j = 0; j < 4; j++) {
                int rb = nw + j * 16 + l15;
                int jb = rb * 8 + ((kh * 4 + quad) ^ (rb & 7));
                bf[j] = *(const bf16x8*)&Bs[jb * 8];
            }
#pragma unroll
            for (int i = 0; i < 2; i++)
#pragma unroll
                for (int j = 0; j < 4; j++)
                    acc[i][j] = __builtin_amdgcn_mfma_f32_16x16x32_bf16(
                        af[i], bf[j], acc[i][j], 0, 0, 0);
        }
    }

    float bcol[4];
#pragma unroll
    for (int j = 0; j < 4; j++) bcol[j] = bias[n0 + nw + j * 16 + l15];

#pragma unroll
    for (int i = 0; i < 2; i++)
#pragma unroll
        for (int j = 0; j < 4; j++)
#pragma unroll
            for (int r = 0; r < 4; r++) {
                int row = m0 + mw + i * 16 + quad * 4 + r;
                int col = n0 + nw + j * 16 + l15;
                out[(size_t)row * DD + col] = acc[i][j][r] + bcol[j];
            }
}

// ---------------------------------------------------------------------------
// MFMA flash attention v4: P never touches LDS.
// The key axis of V^T is bit-permuted in global memory (vt_kernel) so that
// the QK^T output fragment (lane l15=q holds scores for keys kb*16+quad*4+r)
// IS the PV A-operand fragment (keys kh*32+quad*8+delta in permuted order):
//   pa[kh] = { cvtpk(sc[2kh].xy), cvtpk(sc[2kh].zw),
//              cvtpk(sc[2kh+1].xy), cvtpk(sc[2kh+1].zw) }.
// Removes the per-tile P LDS round-trip (4 ds_write_b64 + lgkm wait +
// 2 ds_read_b128) from the critical path and frees 8 KB of LDS (40->32 KB).
// Keeps: 4 waves x 16 q/wave, double-buffered K/V with 1-deep prefetch,
// MFMA row-sum (P x ones; lane layout == o's), packed cvt, libm exp2f
// (raw v_exp_f32 failed accuracy in round 3). s_setprio around MFMA
// clusters (T5: independent co-resident blocks benefit).
// ---------------------------------------------------------------------------
__global__ __launch_bounds__(256) void mfma_attn(
    const bf16* __restrict__ Qb, const bf16* __restrict__ Kb,
    const bf16* __restrict__ Vtg, bf16* __restrict__ ctxb) {
    __shared__ __align__(16) bf16 Ks[2][64 * 64];   // [buf][key][d] swizzled
    __shared__ __align__(16) bf16 Vs[2][64 * 64];   // [buf][d][key'] swizzled

    const int tid = threadIdx.x;
    const int lane = tid & 63;
    const int w = tid >> 6;                  // 0..3
    const int l15 = lane & 15, quad = lane >> 4;
    const int bh = blockIdx.y;
    const int b = bh >> 4, h = bh & 15;
    const int q0 = blockIdx.x * 64;
    const size_t mb = (size_t)b * SS;
    const int hc = h * HD;
    const bf16* Vt_bh = Vtg + (size_t)bh * HD * SS;

    // ---- Q fragments direct from global (held all kernel; B operand) ----
    bf16x8 qf[2];
#pragma unroll
    for (int kh = 0; kh < 2; kh++)
        qf[kh] = *(const bf16x8*)&Qb[(mb + q0 + w * 16 + l15) * DD +
                                     hc + kh * 32 + quad * 8];

    // ones fragment for row-sum MFMA
    bf16x8 onev;
#pragma unroll
    for (int i = 0; i < 8; i++) onev[i] = (bf16)1.0f;

    // ---- hoisted loop-invariant LDS offsets (elements) ----
    int koff[4][2], voff[4][2];
#pragma unroll
    for (int kb = 0; kb < 4; kb++) {
        int rk = kb * 16 + l15;
#pragma unroll
        for (int kh = 0; kh < 2; kh++)
            koff[kb][kh] = (rk * 8 + ((kh * 4 + quad) ^ (rk & 7))) * 8;
    }
#pragma unroll
    for (int nb = 0; nb < 4; nb++) {
        int rv = nb * 16 + l15;
#pragma unroll
        for (int kh = 0; kh < 2; kh++)
            voff[nb][kh] = (rv * 8 + ((kh * 4 + quad) ^ (rv & 7))) * 8;
    }

    // ---- staging pointers (2 chunks each of K and V per thread) ----
    const bf16* gK[2]; const bf16* gV[2]; int lo_[2];
#pragma unroll
    for (int u = 0; u < 2; u++) {
        int j = tid + u * 256;              // chunk 0..511
        int row = j >> 3, cp = j & 7;
        int c = cp ^ (row & 7);
        gK[u] = Kb + (mb + row) * DD + hc + c * 8;
        gV[u] = Vt_bh + (size_t)row * SS + c * 8;
        lo_[u] = j * 8;
    }

    f32x4 o[4], lsum;
    lsum = (f32x4){0.f, 0.f, 0.f, 0.f};
#pragma unroll
    for (int nb = 0; nb < 4; nb++) o[nb] = (f32x4){0.f, 0.f, 0.f, 0.f};

    // ---- prologue: stage tile 0 into buf 0 ----
#pragma unroll
    for (int u = 0; u < 2; u++) {
        glds16(gK[u], &Ks[0][lo_[u]]);  gK[u] += 64 * DD;
        glds16(gV[u], &Vs[0][lo_[u]]);  gV[u] += 64;
    }
    __syncthreads();

    for (int it = 0; it < SS / 64; ++it) {
        const int buf = it & 1;
        // ---- prefetch next tile into the other buffer (in flight over compute)
        if (it + 1 < SS / 64) {
#pragma unroll
            for (int u = 0; u < 2; u++) {
                glds16(gK[u], &Ks[buf ^ 1][lo_[u]]);  gK[u] += 64 * DD;
                glds16(gV[u], &Vs[buf ^ 1][lo_[u]]);  gV[u] += 64;
            }
        }

        // ---- scores: S^T tiles (A = K rows, B = Q) ----
        f32x4 sc[4];
#pragma unroll
        for (int kb = 0; kb < 4; kb++) sc[kb] = (f32x4){0.f, 0.f, 0.f, 0.f};
        __builtin_amdgcn_s_setprio(1);
#pragma unroll
        for (int kb = 0; kb < 4; kb++)
#pragma unroll
            for (int kh = 0; kh < 2; kh++) {
                bf16x8 kf = *(const bf16x8*)&Ks[buf][koff[kb][kh]];
                sc[kb] = __builtin_amdgcn_mfma_f32_16x16x32_bf16(
                    kf, qf[kh], sc[kb], 0, 0, 0);
            }
        __builtin_amdgcn_s_setprio(0);

        // ---- no-max softmax: p = exp2(score) (libm exp2f), packed cvt ----
        // pa[kh] word layout matches the PV A-operand thanks to the V key
        // permutation: word (kb&1)*2+0 = keys {r0,r1}, +1 = {r2,r3}.
        u32x4 pw[2];
#pragma unroll
        for (int kb = 0; kb < 4; kb++) {
            float p0 = exp2f(sc[kb][0]);
            float p1 = exp2f(sc[kb][1]);
            float p2 = exp2f(sc[kb][2]);
            float p3 = exp2f(sc[kb][3]);
            pw[kb >> 1][(kb & 1) * 2 + 0] = cvtpk_bf16(p0, p1);
            pw[kb >> 1][(kb & 1) * 2 + 1] = cvtpk_bf16(p2, p3);
        }
        bf16x8 pfr[2];
        pfr[0] = __builtin_bit_cast(bf16x8, pw[0]);
        pfr[1] = __builtin_bit_cast(bf16x8, pw[1]);

        // ---- PV + row-sum: A = P (in-register), B = V^T (k=key', n=d) ----
        __builtin_amdgcn_s_setprio(1);
#pragma unroll
        for (int kh = 0; kh < 2; kh++) {
            lsum = __builtin_amdgcn_mfma_f32_16x16x32_bf16(
                pfr[kh], onev, lsum, 0, 0, 0);
#pragma unroll
            for (int nb = 0; nb < 4; nb++) {
                bf16x8 vf = *(const bf16x8*)&Vs[buf][voff[nb][kh]];
                o[nb] = __builtin_amdgcn_mfma_f32_16x16x32_bf16(
                    pfr[kh], vf, o[nb], 0, 0, 0);
            }
        }
        __builtin_amdgcn_s_setprio(0);

        // ---- tile boundary: prefetched loads landed; all waves done reading
        __syncthreads();
    }

    // ---- finalize: divide by row sum (lane layout matches o), store bf16 ----
    float li[4];
#pragma unroll
    for (int r = 0; r < 4; r++) li[r] = 1.0f / lsum[r];
#pragma unroll
    for (int nb = 0; nb < 4; nb++)
#pragma unroll
        for (int r = 0; r < 4; r++) {
            int qrow = q0 + w * 16 + quad * 4 + r;
            ctxb[(mb + qrow) * DD + hc + nb * 16 + l15] =
                (bf16)(o[nb][r] * li[r]);
        }
}

// ---------------------------------------------------------------------------
extern "C" void kernel_launch(void* const* d_in, const int* in_sizes, int n_in,
                              void* d_out, int out_size, void* d_ws, size_t ws_size,
                              hipStream_t stream) {
    const float* x  = (const float*)d_in[0];
    const float* Wq = (const float*)d_in[1];
    const float* bq = (const float*)d_in[2];
    const float* Wk = (const float*)d_in[3];
    const float* bk = (const float*)d_in[4];
    const float* Wv = (const float*)d_in[5];
    const float* bv = (const float*)d_in[6];
    const float* Wo = (const float*)d_in[7];
    const float* bo = (const float*)d_in[8];
    float* out = (float*)d_out;

    char* base = (char*)d_ws;
    bf16* xb   = (bf16*)(base);                        //  8 MB (dead after QKV gemm)
    bf16* Wt   = (bf16*)(base + (8ull  << 20));        //  4 x 2 MB
    bf16* Qb   = (bf16*)(base + (16ull << 20));        //  8 MB (pre-scaled)
    bf16* Kb   = (bf16*)(base + (24ull << 20));        //  8 MB
    bf16* Vb   = (bf16*)(base + (32ull << 20));        //  8 MB
    bf16* ctxb = (bf16*)(base + (40ull << 20));        //  8 MB
    bf16* Vtg  = xb;                                   //  reuse xb region

    cvt_x<<<dim3((MM * DD) / (256 * 4)), dim3(256), 0, stream>>>(x, xb);
    cvt_w<<<dim3(16, 16, 4), dim3(256), 0, stream>>>(Wq, Wk, Wv, Wo, Wt);

    mfma_gemm<<<dim3(DD / 128, MM / 128, 3), dim3(256), 0, stream>>>(
        xb, Wt, bq, bk, bv, Qb, Kb, Vb);

    vt_kernel<<<dim3(SS / 64, BB * HH), dim3(256), 0, stream>>>(Vb, Vtg);

    mfma_attn<<<dim3(SS / 64, BB * HH), dim3(256), 0, stream>>>(Qb, Kb, Vtg, ctxb);

    mfma_gemm_out<<<dim3(DD / 128, MM / 64), dim3(256), 0, stream>>>(
        ctxb, Wt + 3ull * DD * DD, bo, out);
}

// Round 6
// 220.460 us; speedup vs baseline: 1.0571x; 1.0106x over previous
//
#include <hip/hip_runtime.h>
#include <hip/hip_bf16.h>
#include <math.h>

#define BB 2
#define SS 2048
#define DD 1024
#define HH 16
#define HD 64
#define MM (BB * SS)   // 4096
#define NT (SS / 64)   // 32 key tiles

typedef __bf16 bf16;
typedef __attribute__((ext_vector_type(8))) __bf16 bf16x8;
typedef __attribute__((ext_vector_type(4))) __bf16 bf16x4;
typedef __attribute__((ext_vector_type(4))) float f32x4;
typedef __attribute__((ext_vector_type(4))) unsigned u32x4;

#define QSCL 0.18033688011112042f   // log2(e)/8, folded into Q at projection

// async global->LDS, 16B per lane. LDS dest must be wave-uniform base + lane*16.
__device__ __forceinline__ void glds16(const bf16* g, bf16* l) {
    __builtin_amdgcn_global_load_lds(
        (const __attribute__((address_space(1))) void*)g,
        (__attribute__((address_space(3))) void*)l, 16, 0, 0);
}

// packed f32x2 -> bf16x2 (no builtin on gfx950; T12 primitive)
__device__ __forceinline__ unsigned cvtpk_bf16(float a, float b) {
    unsigned r;
    asm("v_cvt_pk_bf16_f32 %0, %1, %2" : "=v"(r) : "v"(a), "v"(b));
    return r;
}

// ---------------------------------------------------------------------------
// Prep 1: x (fp32) -> xb (bf16).  4M elements, 4/thread.
// ---------------------------------------------------------------------------
__global__ __launch_bounds__(256) void cvt_x(const float* __restrict__ x,
                                             bf16* __restrict__ xb) {
    int i = (blockIdx.x * 256 + threadIdx.x) * 4;
    float4 v = *(const float4*)(x + i);
    bf16x4 o;
    o[0] = (bf16)v.x; o[1] = (bf16)v.y; o[2] = (bf16)v.z; o[3] = (bf16)v.w;
    *(bf16x4*)(xb + i) = o;
}

// ---------------------------------------------------------------------------
// Prep 2: W[k][n] fp32 -> Wt[n][k] bf16 (4 weights via z). 64x64 LDS transpose.
// ---------------------------------------------------------------------------
__global__ __launch_bounds__(256) void cvt_w(
    const float* __restrict__ W0, const float* __restrict__ W1,
    const float* __restrict__ W2, const float* __restrict__ W3,
    bf16* __restrict__ Wt) {
    const float* W = (blockIdx.z == 0) ? W0 : (blockIdx.z == 1) ? W1
                   : (blockIdx.z == 2) ? W2 : W3;
    bf16* dst = Wt + (size_t)blockIdx.z * DD * DD;

    __shared__ float T[64][65];
    int k0 = blockIdx.y * 64, n0 = blockIdx.x * 64;
    int tr = threadIdx.x >> 4, tc = (threadIdx.x & 15) * 4;
#pragma unroll
    for (int u = 0; u < 4; u++) {
        int r = tr + u * 16;
        float4 v = *(const float4*)&W[(size_t)(k0 + r) * DD + n0 + tc];
        T[tc + 0][r] = v.x; T[tc + 1][r] = v.y;
        T[tc + 2][r] = v.z; T[tc + 3][r] = v.w;
    }
    __syncthreads();
#pragma unroll
    for (int u = 0; u < 4; u++) {
        int r = tr + u * 16;   // n index
        bf16x4 o;
        o[0] = (bf16)T[r][tc + 0]; o[1] = (bf16)T[r][tc + 1];
        o[2] = (bf16)T[r][tc + 2]; o[3] = (bf16)T[r][tc + 3];
        *(bf16x4*)&dst[(size_t)(n0 + r) * DD + k0 + tc] = o;
    }
}

// ---------------------------------------------------------------------------
// Prep 3: V [token][h*64+d] bf16 -> Vt_g [bh][d][s'] bf16, with the key axis
// BIT-PERMUTED within each 64-token tile:  token m = [b5 b4 b3 b2 b1 b0]
// lands at column f(m) = [b5][b3 b2][b4][b1 b0].
// This makes the attention QK^T output fragment layout IDENTICAL to the PV
// A-operand fragment layout, so P never touches LDS (see mfma_attn).
// ---------------------------------------------------------------------------
__global__ __launch_bounds__(256) void vt_kernel(const bf16* __restrict__ V,
                                                 bf16* __restrict__ Vt) {
    const int bh = blockIdx.y;
    const int b = bh >> 4, h = bh & 15;
    const int s0 = blockIdx.x * 64;

    __shared__ bf16 T[64][72];
    const int r = threadIdx.x >> 2;            // 0..63
    const int C = threadIdx.x & 3;             // 0..3
    const int c0 = C * 16;                     // d-offset for load phase

    const bf16* src = V + ((size_t)(b * SS + s0 + r)) * DD + h * HD + c0;
    *(bf16x8*)&T[r][c0]     = *(const bf16x8*)(src);
    *(bf16x8*)&T[r][c0 + 8] = *(const bf16x8*)(src + 8);
    __syncthreads();

    const int M0 = (C >> 1) * 32 + (C & 1) * 8;
    bf16x8 o0, o1;
#pragma unroll
    for (int i = 0; i < 4; i++) o0[i]     = T[M0 + i][r];
#pragma unroll
    for (int i = 0; i < 4; i++) o0[4 + i] = T[M0 + 16 + i][r];
#pragma unroll
    for (int i = 0; i < 4; i++) o1[i]     = T[M0 + 4 + i][r];
#pragma unroll
    for (int i = 0; i < 4; i++) o1[4 + i] = T[M0 + 20 + i][r];
    bf16* dst = Vt + ((size_t)bh * HD + r) * SS + s0 + c0;
    *(bf16x8*)dst       = o0;
    *(bf16x8*)(dst + 8) = o1;
}

// ---------------------------------------------------------------------------
// MFMA GEMM (R3 form): C[m][n] = sum_k A[m][k] * Wt[n][k] + bias[n]
// 128x128 tile, BK=64, 256 threads (4 waves, each 64x64). XOR-swizzled LDS.
// z selects weight/bias/dst for QKV (z=0 output scaled by QSCL).
// ---------------------------------------------------------------------------
__global__ __launch_bounds__(256) void mfma_gemm(
    const bf16* __restrict__ A, const bf16* __restrict__ Wt0,
    const float* __restrict__ b0, const float* __restrict__ b1,
    const float* __restrict__ b2,
    bf16* __restrict__ o0, bf16* __restrict__ o1, bf16* __restrict__ o2) {
    const int z = blockIdx.z;
    const bf16* Wt = Wt0 + (size_t)z * DD * DD;
    const float* bias = (z == 0) ? b0 : (z == 1) ? b1 : b2;
    bf16* dstb = (z == 0) ? o0 : (z == 1) ? o1 : o2;
    const float scl = (z == 0) ? QSCL : 1.0f;

    __shared__ __align__(16) bf16 As[128 * 64];
    __shared__ __align__(16) bf16 Bs[128 * 64];

    const int tid = threadIdx.x;
    const int lane = tid & 63;
    const int w = tid >> 6;
    const int l15 = lane & 15, quad = lane >> 4;
    const int m0 = blockIdx.y * 128;
    const int n0 = blockIdx.x * 128;
    const int mw = (w & 1) * 64;
    const int nw = (w >> 1) * 64;

    f32x4 acc[4][4];
#pragma unroll
    for (int i = 0; i < 4; i++)
#pragma unroll
        for (int j = 0; j < 4; j++) acc[i][j] = (f32x4){0.f, 0.f, 0.f, 0.f};

    for (int kt = 0; kt < DD; kt += 64) {
        __syncthreads();
#pragma unroll
        for (int u = 0; u < 4; u++) {
            int j = tid + u * 256;          // chunk 0..1023
            int row = j >> 3, cp = j & 7;
            int c = cp ^ (row & 7);         // global 16B-chunk within row
            glds16(A  + (size_t)(m0 + row) * DD + kt + c * 8, &As[j * 8]);
            glds16(Wt + (size_t)(n0 + row) * DD + kt + c * 8, &Bs[j * 8]);
        }
        __syncthreads();

#pragma unroll
        for (int kh = 0; kh < 2; kh++) {
            bf16x8 af[4], bf[4];
#pragma unroll
            for (int i = 0; i < 4; i++) {
                int ra = mw + i * 16 + l15;
                int ja = ra * 8 + ((kh * 4 + quad) ^ (ra & 7));
                af[i] = *(const bf16x8*)&As[ja * 8];
                int rb = nw + i * 16 + l15;
                int jb = rb * 8 + ((kh * 4 + quad) ^ (rb & 7));
                bf[i] = *(const bf16x8*)&Bs[jb * 8];
            }
#pragma unroll
            for (int i = 0; i < 4; i++)
#pragma unroll
                for (int j = 0; j < 4; j++)
                    acc[i][j] = __builtin_amdgcn_mfma_f32_16x16x32_bf16(
                        af[i], bf[j], acc[i][j], 0, 0, 0);
        }
    }

    float bcol[4];
#pragma unroll
    for (int j = 0; j < 4; j++) bcol[j] = bias[n0 + nw + j * 16 + l15];

#pragma unroll
    for (int i = 0; i < 4; i++)
#pragma unroll
        for (int j = 0; j < 4; j++)
#pragma unroll
            for (int r = 0; r < 4; r++) {
                int row = m0 + mw + i * 16 + quad * 4 + r;
                int col = n0 + nw + j * 16 + l15;
                dstb[(size_t)row * DD + col] =
                    (bf16)((acc[i][j][r] + bcol[j]) * scl);
            }
}

// ---------------------------------------------------------------------------
// Out-proj GEMM: 64x128 tile (M x N), BK=64, 256 threads (4 waves, 32x64).
// ---------------------------------------------------------------------------
__global__ __launch_bounds__(256) void mfma_gemm_out(
    const bf16* __restrict__ A, const bf16* __restrict__ Wt,
    const float* __restrict__ bias, float* __restrict__ out) {
    __shared__ __align__(16) bf16 As[64 * 64];
    __shared__ __align__(16) bf16 Bs[128 * 64];

    const int tid = threadIdx.x;
    const int lane = tid & 63;
    const int w = tid >> 6;
    const int l15 = lane & 15, quad = lane >> 4;
    const int m0 = blockIdx.y * 64;
    const int n0 = blockIdx.x * 128;
    const int mw = (w & 1) * 32;
    const int nw = (w >> 1) * 64;

    f32x4 acc[2][4];
#pragma unroll
    for (int i = 0; i < 2; i++)
#pragma unroll
        for (int j = 0; j < 4; j++) acc[i][j] = (f32x4){0.f, 0.f, 0.f, 0.f};

    for (int kt = 0; kt < DD; kt += 64) {
        __syncthreads();
#pragma unroll
        for (int u = 0; u < 2; u++) {      // As: 512 chunks
            int j = tid + u * 256;
            int row = j >> 3, c = (j & 7) ^ (row & 7);
            glds16(A + (size_t)(m0 + row) * DD + kt + c * 8, &As[j * 8]);
        }
#pragma unroll
        for (int u = 0; u < 4; u++) {      // Bs: 1024 chunks
            int j = tid + u * 256;
            int row = j >> 3, c = (j & 7) ^ (row & 7);
            glds16(Wt + (size_t)(n0 + row) * DD + kt + c * 8, &Bs[j * 8]);
        }
        __syncthreads();

#pragma unroll
        for (int kh = 0; kh < 2; kh++) {
            bf16x8 af[2], bf[4];
#pragma unroll
            for (int i = 0; i < 2; i++) {
                int ra = mw + i * 16 + l15;
                int ja = ra * 8 + ((kh * 4 + quad) ^ (ra & 7));
                af[i] = *(const bf16x8*)&As[ja * 8];
            }
#pragma unroll
            for (int j = 0; j < 4; j++) {
                int rb = nw + j * 16 + l15;
                int jb = rb * 8 + ((kh * 4 + quad) ^ (rb & 7));
                bf[j] = *(const bf16x8*)&Bs[jb * 8];
            }
#pragma unroll
            for (int i = 0; i < 2; i++)
#pragma unroll
                for (int j = 0; j < 4; j++)
                    acc[i][j] = __builtin_amdgcn_mfma_f32_16x16x32_bf16(
                        af[i], bf[j], acc[i][j], 0, 0, 0);
        }
    }

    float bcol[4];
#pragma unroll
    for (int j = 0; j < 4; j++) bcol[j] = bias[n0 + nw + j * 16 + l15];

#pragma unroll
    for (int i = 0; i < 2; i++)
#pragma unroll
        for (int j = 0; j < 4; j++)
#pragma unroll
            for (int r = 0; r < 4; r++) {
                int row = m0 + mw + i * 16 + quad * 4 + r;
                int col = n0 + nw + j * 16 + l15;
                out[(size_t)row * DD + col] = acc[i][j][r] + bcol[j];
            }
}

// ---------------------------------------------------------------------------
// MFMA flash attention v5: 2-phase cross-tile pipeline.
// Per iteration:
//   prefetch(t+1)          [async glds16 -> buf^1]
//   softmax(t)             [VALU; overlaps prefetch flight]
//   barrier A              [K/V for t+1 landed across all waves]
//   setprio(1): QK(t+1) + PV(t) + lsum(t)   [one pure-MFMA cluster]
//   setprio(0)
//   barrier B              [all waves done reading buf before prefetch(t+2)
//                           overwrites it next iteration]
// Accumulation order per tile is unchanged -> numerics identical to v4.
// Keeps: P-in-register via V key bit-permutation (no P LDS), MFMA row-sum,
// packed cvtpk, libm exp2f (builtin failed accuracy in round 3).
// ---------------------------------------------------------------------------
__global__ __launch_bounds__(256) void mfma_attn(
    const bf16* __restrict__ Qb, const bf16* __restrict__ Kb,
    const bf16* __restrict__ Vtg, bf16* __restrict__ ctxb) {
    __shared__ __align__(16) bf16 Ks[2][64 * 64];   // [buf][key][d] swizzled
    __shared__ __align__(16) bf16 Vs[2][64 * 64];   // [buf][d][key'] swizzled

    const int tid = threadIdx.x;
    const int lane = tid & 63;
    const int w = tid >> 6;                  // 0..3
    const int l15 = lane & 15, quad = lane >> 4;
    const int bh = blockIdx.y;
    const int b = bh >> 4, h = bh & 15;
    const int q0 = blockIdx.x * 64;
    const size_t mb = (size_t)b * SS;
    const int hc = h * HD;
    const bf16* Vt_bh = Vtg + (size_t)bh * HD * SS;

    // ---- Q fragments direct from global (held all kernel; B operand) ----
    bf16x8 qf[2];
#pragma unroll
    for (int kh = 0; kh < 2; kh++)
        qf[kh] = *(const bf16x8*)&Qb[(mb + q0 + w * 16 + l15) * DD +
                                     hc + kh * 32 + quad * 8];

    // ones fragment for row-sum MFMA
    bf16x8 onev;
#pragma unroll
    for (int i = 0; i < 8; i++) onev[i] = (bf16)1.0f;

    // ---- hoisted loop-invariant LDS offsets (elements) ----
    int koff[4][2], voff[4][2];
#pragma unroll
    for (int kb = 0; kb < 4; kb++) {
        int rk = kb * 16 + l15;
#pragma unroll
        for (int kh = 0; kh < 2; kh++)
            koff[kb][kh] = (rk * 8 + ((kh * 4 + quad) ^ (rk & 7))) * 8;
    }
#pragma unroll
    for (int nb = 0; nb < 4; nb++) {
        int rv = nb * 16 + l15;
#pragma unroll
        for (int kh = 0; kh < 2; kh++)
            voff[nb][kh] = (rv * 8 + ((kh * 4 + quad) ^ (rv & 7))) * 8;
    }

    // ---- staging pointers (2 chunks each of K and V per thread) ----
    const bf16* gK[2]; const bf16* gV[2]; int lo_[2];
#pragma unroll
    for (int u = 0; u < 2; u++) {
        int j = tid + u * 256;              // chunk 0..511
        int row = j >> 3, cp = j & 7;
        int c = cp ^ (row & 7);
        gK[u] = Kb + (mb + row) * DD + hc + c * 8;
        gV[u] = Vt_bh + (size_t)row * SS + c * 8;
        lo_[u] = j * 8;
    }

    f32x4 o[4], lsum;
    lsum = (f32x4){0.f, 0.f, 0.f, 0.f};
#pragma unroll
    for (int nb = 0; nb < 4; nb++) o[nb] = (f32x4){0.f, 0.f, 0.f, 0.f};

    // ---- prologue: stage tile 0 into buf 0, then QK(0) ----
#pragma unroll
    for (int u = 0; u < 2; u++) {
        glds16(gK[u], &Ks[0][lo_[u]]);  gK[u] += 64 * DD;
        glds16(gV[u], &Vs[0][lo_[u]]);  gV[u] += 64;
    }
    __syncthreads();

    f32x4 scA[4];
#pragma unroll
    for (int kb = 0; kb < 4; kb++) scA[kb] = (f32x4){0.f, 0.f, 0.f, 0.f};
#pragma unroll
    for (int kb = 0; kb < 4; kb++)
#pragma unroll
        for (int kh = 0; kh < 2; kh++) {
            bf16x8 kf = *(const bf16x8*)&Ks[0][koff[kb][kh]];
            scA[kb] = __builtin_amdgcn_mfma_f32_16x16x32_bf16(
                kf, qf[kh], scA[kb], 0, 0, 0);
        }

    int buf = 0;
    for (int it = 0; it < NT; ++it) {
        const bool more = (it + 1 < NT);
        // ---- prefetch t+1 into the other buffer (flight hidden by softmax)
        if (more) {
#pragma unroll
            for (int u = 0; u < 2; u++) {
                glds16(gK[u], &Ks[buf ^ 1][lo_[u]]);  gK[u] += 64 * DD;
                glds16(gV[u], &Vs[buf ^ 1][lo_[u]]);  gV[u] += 64;
            }
        }

        // ---- softmax(t): p = exp2(score) (libm), packed cvt -> PV A-frags
        u32x4 pw[2];
#pragma unroll
        for (int kb = 0; kb < 4; kb++) {
            float p0 = exp2f(scA[kb][0]);
            float p1 = exp2f(scA[kb][1]);
            float p2 = exp2f(scA[kb][2]);
            float p3 = exp2f(scA[kb][3]);
            pw[kb >> 1][(kb & 1) * 2 + 0] = cvtpk_bf16(p0, p1);
            pw[kb >> 1][(kb & 1) * 2 + 1] = cvtpk_bf16(p2, p3);
        }
        bf16x8 pfr[2];
        pfr[0] = __builtin_bit_cast(bf16x8, pw[0]);
        pfr[1] = __builtin_bit_cast(bf16x8, pw[1]);

        // ---- barrier A: K/V(t+1) landed for all waves ----
        __syncthreads();

        // ---- one MFMA cluster: QK(t+1) then PV(t)+lsum(t) ----
        __builtin_amdgcn_s_setprio(1);
        f32x4 scB[4];
#pragma unroll
        for (int kb = 0; kb < 4; kb++) scB[kb] = (f32x4){0.f, 0.f, 0.f, 0.f};
        if (more) {
#pragma unroll
            for (int kb = 0; kb < 4; kb++)
#pragma unroll
                for (int kh = 0; kh < 2; kh++) {
                    bf16x8 kf = *(const bf16x8*)&Ks[buf ^ 1][koff[kb][kh]];
                    scB[kb] = __builtin_amdgcn_mfma_f32_16x16x32_bf16(
                        kf, qf[kh], scB[kb], 0, 0, 0);
                }
        }
#pragma unroll
        for (int kh = 0; kh < 2; kh++) {
            lsum = __builtin_amdgcn_mfma_f32_16x16x32_bf16(
                pfr[kh], onev, lsum, 0, 0, 0);
#pragma unroll
            for (int nb = 0; nb < 4; nb++) {
                bf16x8 vf = *(const bf16x8*)&Vs[buf][voff[nb][kh]];
                o[nb] = __builtin_amdgcn_mfma_f32_16x16x32_bf16(
                    pfr[kh], vf, o[nb], 0, 0, 0);
            }
        }
        __builtin_amdgcn_s_setprio(0);

        // ---- barrier B: all waves done reading buf before prefetch(t+2)
        __syncthreads();

#pragma unroll
        for (int kb = 0; kb < 4; kb++) scA[kb] = scB[kb];
        buf ^= 1;
    }

    // ---- finalize: divide by row sum (lane layout matches o), store bf16 ----
    float li[4];
#pragma unroll
    for (int r = 0; r < 4; r++) li[r] = 1.0f / lsum[r];
#pragma unroll
    for (int nb = 0; nb < 4; nb++)
#pragma unroll
        for (int r = 0; r < 4; r++) {
            int qrow = q0 + w * 16 + quad * 4 + r;
            ctxb[(mb + qrow) * DD + hc + nb * 16 + l15] =
                (bf16)(o[nb][r] * li[r]);
        }
}

// ---------------------------------------------------------------------------
extern "C" void kernel_launch(void* const* d_in, const int* in_sizes, int n_in,
                              void* d_out, int out_size, void* d_ws, size_t ws_size,
                              hipStream_t stream) {
    const float* x  = (const float*)d_in[0];
    const float* Wq = (const float*)d_in[1];
    const float* bq = (const float*)d_in[2];
    const float* Wk = (const float*)d_in[3];
    const float* bk = (const float*)d_in[4];
    const float* Wv = (const float*)d_in[5];
    const float* bv = (const float*)d_in[6];
    const float* Wo = (const float*)d_in[7];
    const float* bo = (const float*)d_in[8];
    float* out = (float*)d_out;

    char* base = (char*)d_ws;
    bf16* xb   = (bf16*)(base);                        //  8 MB (dead after QKV gemm)
    bf16* Wt   = (bf16*)(base + (8ull  << 20));        //  4 x 2 MB
    bf16* Qb   = (bf16*)(base + (16ull << 20));        //  8 MB (pre-scaled)
    bf16* Kb   = (bf16*)(base + (24ull << 20));        //  8 MB
    bf16* Vb   = (bf16*)(base + (32ull << 20));        //  8 MB
    bf16* ctxb = (bf16*)(base + (40ull << 20));        //  8 MB
    bf16* Vtg  = xb;                                   //  reuse xb region

    cvt_x<<<dim3((MM * DD) / (256 * 4)), dim3(256), 0, stream>>>(x, xb);
    cvt_w<<<dim3(16, 16, 4), dim3(256), 0, stream>>>(Wq, Wk, Wv, Wo, Wt);

    mfma_gemm<<<dim3(DD / 128, MM / 128, 3), dim3(256), 0, stream>>>(
        xb, Wt, bq, bk, bv, Qb, Kb, Vb);

    vt_kernel<<<dim3(SS / 64, BB * HH), dim3(256), 0, stream>>>(Vb, Vtg);

    mfma_attn<<<dim3(SS / 64, BB * HH), dim3(256), 0, stream>>>(Qb, Kb, Vtg, ctxb);

    mfma_gemm_out<<<dim3(DD / 128, MM / 64), dim3(256), 0, stream>>>(
        ctxb, Wt + 3ull * DD * DD, bo, out);
}